// Round 7
// baseline (807.870 us; speedup 1.0000x reference)
//
#include <hip/hip_runtime.h>
#include <hip/hip_bf16.h>
#include <float.h>

#define BATCH 8
#define CDIM 64
#define NPTS 4096
#define KNN 20
#define KSEL 32
#define BUFTHR 48     // truncate when a row's count exceeds this
#define BUFCAP 64     // slots used per row (1-elem-per-lane select limit)
#define BUFSTR 68     // row stride in LDS (bank stagger)
#define BN_EPS 1e-5f
#define NEG_SLOPE 0.2f

typedef __attribute__((ext_vector_type(8))) short short8;
typedef __attribute__((ext_vector_type(4))) float float4v;
typedef unsigned short ushort;
typedef unsigned int uint;
typedef unsigned long long ull;

__device__ __forceinline__ ushort f2bf(float f) {
    uint u = __float_as_uint(f);
    u += 0x7FFF + ((u >> 16) & 1);            // round-to-nearest-even
    return (ushort)(u >> 16);
}
__device__ __forceinline__ int mbcnt64(ull m) {
    int c = __builtin_amdgcn_mbcnt_lo((uint)m, 0);
    return __builtin_amdgcn_mbcnt_hi((uint)(m >> 32), c);
}

// Find 33rd-smallest key among buf[0..cv) (cv <= 64, one entry per lane),
// compact keys < K33 to slots [0..newc). newc==32 when cv>=33, else cv.
// Keys are distinct (unique idx bits); key bit31 is always 0.
__device__ __forceinline__ uint sel33_64(uint* __restrict__ buf,
                                         int cv, int lane, int& newc) {
    uint e0 = (lane < cv) ? buf[lane] : 0xFFFFFFFFu;
    uint p = 0;
    #pragma unroll 1
    for (int bit = 30; bit >= 0; --bit) {
        uint t = p | (1u << bit);
        ull mA = __ballot(e0 < t);
        if (__popcll(mA) < 33) p = t;   // uniform
    }
    ull mA = __ballot(e0 < p);
    if (e0 < p) buf[mbcnt64(mA)] = e0;
    newc = __popcll(mA);
    return p;
}

// ---------------------------------------------------------------------------
// K1: x [B,C,N] -> xt [B,N,64] fp32, xh bf16, sq[b,n].
// ---------------------------------------------------------------------------
__global__ void k_prep(const float* __restrict__ x,
                       float* __restrict__ xt,
                       ushort* __restrict__ xh,
                       float* __restrict__ sq) {
    int gid = blockIdx.x * 256 + threadIdx.x;     // [0, B*N)
    int b = gid >> 12;
    int n = gid & (NPTS - 1);
    const float* xb = x + (size_t)b * CDIM * NPTS + n;
    float acc = 0.f;
    float4* xtv = (float4*)(xt + ((size_t)gid << 6));
    uint2* xhp = (uint2*)(xh + ((size_t)gid << 6));
    #pragma unroll
    for (int q = 0; q < 16; ++q) {
        float v[4]; ushort h[4];
        #pragma unroll
        for (int j = 0; j < 4; ++j) {
            float tv = xb[(q * 4 + j) * NPTS];    // coalesced across n
            v[j] = tv;
            acc = fmaf(tv, tv, acc);
            h[j] = f2bf(tv);
        }
        xtv[q] = make_float4(v[0], v[1], v[2], v[3]);
        uint2 ph;
        ph.x = (uint)h[0] | ((uint)h[1] << 16);
        ph.y = (uint)h[2] | ((uint)h[3] << 16);
        xhp[q] = ph;
    }
    sq[gid] = acc;
}

// ---------------------------------------------------------------------------
// K2: p = W1 @ x, z = (W2-W1) @ x, stored transposed: pt/zt [B,N,64]
// ---------------------------------------------------------------------------
__global__ void k_pz(const float* __restrict__ xt, const float* __restrict__ W,
                     float* __restrict__ pt, float* __restrict__ zt) {
    int b  = blockIdx.x >> 6;
    int n0 = (blockIdx.x & 63) << 6;
    int lane = threadIdx.x & 63;
    int w = threadIdx.x >> 6;
    int n = n0 + lane;
    size_t rowoff = ((size_t)(b * NPTS + n)) << 6;
    const float4* xrow = (const float4*)(xt + rowoff);
    float acc1[16], acc2[16];
    #pragma unroll
    for (int i = 0; i < 16; ++i) { acc1[i] = 0.f; acc2[i] = 0.f; }
    #pragma unroll
    for (int cg = 0; cg < 4; ++cg) {
        float xv[16];
        #pragma unroll
        for (int q = 0; q < 4; ++q) {
            float4 t = xrow[cg * 4 + q];
            xv[q*4] = t.x; xv[q*4+1] = t.y; xv[q*4+2] = t.z; xv[q*4+3] = t.w;
        }
        #pragma unroll
        for (int oi = 0; oi < 16; ++oi) {
            int o = (w << 4) + oi;
            const float* wr = W + o * 128 + cg * 16;
            float a1 = acc1[oi], a2 = acc2[oi];
            #pragma unroll
            for (int j = 0; j < 16; ++j) {
                a1 = fmaf(wr[j],      xv[j], a1);
                a2 = fmaf(wr[64 + j], xv[j], a2);
            }
            acc1[oi] = a1; acc2[oi] = a2;
        }
    }
    float4* pv = (float4*)(pt + rowoff + (w << 4));
    float4* zv = (float4*)(zt + rowoff + (w << 4));
    #pragma unroll
    for (int q = 0; q < 4; ++q) {
        pv[q] = make_float4(acc1[q*4], acc1[q*4+1], acc1[q*4+2], acc1[q*4+3]);
        zv[q] = make_float4(acc2[q*4]   - acc1[q*4],
                            acc2[q*4+1] - acc1[q*4+1],
                            acc2[q*4+2] - acc1[q*4+2],
                            acc2[q*4+3] - acc1[q*4+3]);
    }
}

// ---------------------------------------------------------------------------
// K3: candidate-split barrier-light kNN, register-direct segmented scan.
// Block = 256 thr = 4 independent waves sharing 16 rows; wave q scans the
// disjoint candidate quarter [1024q, 1024q+1024) (16 chunks of 64), keeping
// a private top-32 per row in LDS (64 slots/row, 1-elem-per-lane select33).
// Per chunk: 8 MFMAs -> acc reg r at lane = (row 4*quad+r, cand lane&15);
// selection runs straight out of the accumulator via one 64-lane ballot per
// (tile,r) covering 4 rows x 16 cands; per-quad 16-bit slice gives count &
// rank. Overflow: write-then-truncate, uniform check per tile (growth<=16,
// 48+16<=64 slots). Epilogue: pre-truncate own rows to exact quarter-top-32,
// ONE __syncthreads, then each wave merges 4 rows (4x32=128 keys, 2-elem
// bisection) and writes the exact top-32 set to knn32.
// R6 lesson: __launch_bounds__(256,8) capped VGPR at 64 < ~90 live state ->
// scratch spills (704 MB WRITE_SIZE/dispatch, kernel went HBM-bound).
// (256,4) gives a 128-VGPR budget: no spill, 4 waves/SIMD occupancy.
// ---------------------------------------------------------------------------
__global__ void __launch_bounds__(256, 4) k_knn(
        const ushort* __restrict__ xh,
        const float* __restrict__ sq, ushort* __restrict__ knn32) {
    __shared__ uint wbufA[4][16][BUFSTR];   // [wave][row][slot] 17.4 KB

    int lane = threadIdx.x & 63;
    int wv   = threadIdx.x >> 6;          // candidate quarter 0..3
    int b    = blockIdx.x >> 8;           // 256 blocks per batch
    int r0   = (blockIdx.x & 255) << 4;   // block's 16 rows
    int col  = lane & 15;
    int quad = lane >> 4;
    int cb   = wv << 10;                  // quarter candidate base

    uint (* __restrict__ wb)[BUFSTR] = wbufA[wv];

    // A fragments (chunk-invariant): row = r0 + col, k = quad*8 + j
    size_t arow = ((size_t)(b * NPTS + r0 + col)) << 6;
    short8 ah0 = *(const short8*)(xh + arow + quad * 8);
    short8 ah1 = *(const short8*)(xh + arow + 32 + quad * 8);

    const ushort* xhb = xh + (((size_t)b * NPTS) << 6);
    const float* sqb = sq + b * NPTS;

    // per-lane selection state for rows r0 + 4*quad + r
    uint tau[4]; int cnt[4]; float sqr[4];
    #pragma unroll
    for (int r = 0; r < 4; ++r) {
        tau[r] = 0xFFFFFFFFu; cnt[r] = 0;
        sqr[r] = sqb[r0 + (quad << 2) + r];
    }

    // prologue: B-frags + candidate-sq for chunk 0 of this quarter
    short8 f[8]; float svt[4];
    #pragma unroll
    for (int j = 0; j < 4; ++j) {
        const ushort* p =
            xhb + (((size_t)(cb + (j << 4) + col)) << 6) + (quad << 3);
        f[2*j]   = *(const short8*)p;
        f[2*j+1] = *(const short8*)(p + 32);
        svt[j]   = sqb[cb + (j << 4) + col];
    }

    #pragma unroll 1
    for (int c = 0; c < 16; ++c) {
        int m0 = cb + (c << 6);

        // MFMA phase: 4 tiles (rows r0..r0+16 x cands m0+16j..+16)
        float4v a0, a1, a2, a3;
        {
            float4v z = {0.f, 0.f, 0.f, 0.f};
            a0 = __builtin_amdgcn_mfma_f32_16x16x32_bf16(ah0, f[0], z,  0, 0, 0);
            a0 = __builtin_amdgcn_mfma_f32_16x16x32_bf16(ah1, f[1], a0, 0, 0, 0);
            a1 = __builtin_amdgcn_mfma_f32_16x16x32_bf16(ah0, f[2], z,  0, 0, 0);
            a1 = __builtin_amdgcn_mfma_f32_16x16x32_bf16(ah1, f[3], a1, 0, 0, 0);
            a2 = __builtin_amdgcn_mfma_f32_16x16x32_bf16(ah0, f[4], z,  0, 0, 0);
            a2 = __builtin_amdgcn_mfma_f32_16x16x32_bf16(ah1, f[5], a2, 0, 0, 0);
            a3 = __builtin_amdgcn_mfma_f32_16x16x32_bf16(ah0, f[6], z,  0, 0, 0);
            a3 = __builtin_amdgcn_mfma_f32_16x16x32_bf16(ah1, f[7], a3, 0, 0, 0);
        }

        // prefetch next chunk's frags + cand-sq (latency hidden under scan)
        int nc = (c + 1) & 15;
        float svn[4];
        #pragma unroll
        for (int j = 0; j < 4; ++j) {
            const ushort* p = xhb +
                (((size_t)(cb + (nc << 6) + (j << 4) + col)) << 6) + (quad << 3);
            f[2*j]   = *(const short8*)p;
            f[2*j+1] = *(const short8*)(p + 32);
            svn[j]   = sqb[cb + (nc << 6) + (j << 4) + col];
        }

        // scan phase: register-direct segmented append, one ballot per
        // (tile, r) covering 4 rows x 16 candidates
        #pragma unroll
        for (int j = 0; j < 4; ++j) {
            const float4v aj = (j == 0) ? a0 : (j == 1) ? a1 : (j == 2) ? a2 : a3;
            #pragma unroll
            for (int r = 0; r < 4; ++r) {
                float dval = fmaxf(fmaf(-2.f, aj[r], svt[j] + sqr[r]), 0.f);
                uint key = (__float_as_uint(dval) & 0xFFFFF000u)
                           | (uint)(m0 + (j << 4) + col);
                ull m = __ballot(key < tau[r]);
                uint seg = (uint)(m >> (quad << 4)) & 0xFFFFu;
                if (key < tau[r]) {
                    int rank = __popc(seg & ((1u << col) - 1u));
                    wb[(quad << 2) + r][cnt[r] + rank] = key;
                }
                cnt[r] += __popc(seg);
            }
            // uniform overflow check per tile (growth <= 16/row per tile)
            bool ov = (cnt[0] > BUFTHR) | (cnt[1] > BUFTHR) |
                      (cnt[2] > BUFTHR) | (cnt[3] > BUFTHR);
            if (__ballot(ov)) {
                #pragma unroll
                for (int r = 0; r < 4; ++r) {
                    ull mv = __ballot(cnt[r] > BUFTHR);
                    while (mv) {
                        int q = (int)(__builtin_ctzll(mv)) >> 4;
                        int cv = __shfl(cnt[r], q << 4);
                        int newc;
                        uint p = sel33_64(wb[(q << 2) + r], cv, lane, newc);
                        if (quad == q) { tau[r] = p; cnt[r] = newc; }
                        mv &= ~(0xFFFFull << (q << 4));
                    }
                }
            }
        }
        #pragma unroll
        for (int j = 0; j < 4; ++j) svt[j] = svn[j];
    }

    // pre-truncate own 16 rows to the exact quarter-top-32
    #pragma unroll 1
    for (int rr = 0; rr < 16; ++rr) {
        int cv = __shfl(cnt[rr & 3], (rr >> 2) << 4);
        if (cv > 32) { int nc2; sel33_64(wb[rr], cv, lane, nc2); }
    }

    __syncthreads();   // the only block barrier

    // merge: wave wv handles rows (wv*4 .. wv*4+4); 128 keys -> exact top-32
    #pragma unroll 1
    for (int i = 0; i < 4; ++i) {
        int rr = (wv << 2) + i;
        uint e0 = wbufA[lane >> 5][rr][lane & 31];
        uint e1 = wbufA[2 + (lane >> 5)][rr][lane & 31];
        uint p = 0;
        #pragma unroll 1
        for (int bit = 30; bit >= 0; --bit) {
            uint t = p | (1u << bit);
            ull mA = __ballot(e0 < t);
            ull mB = __ballot(e1 < t);
            if (__popcll(mA) + __popcll(mB) < 33) p = t;   // uniform
        }
        ull mA = __ballot(e0 < p);
        ull mB = __ballot(e1 < p);
        int pA = __popcll(mA);
        size_t rowg = (size_t)(b * NPTS + r0 + rr) * KSEL;
        if (e0 < p) knn32[rowg + mbcnt64(mA)]      = (ushort)(e0 & 0xFFFu);
        if (e1 < p) knn32[rowg + pA + mbcnt64(mB)] = (ushort)(e1 & 0xFFFu);
    }
}

// ---------------------------------------------------------------------------
// K3b: exact fp32 refinement — TWO rows per wave (half-wave per row, no idle
// lanes): 32 candidates in each half's lanes, exact fp32 distances, rank
// lexicographically (dist, idx) per np tie rule, emit top-20 set.
// ---------------------------------------------------------------------------
__global__ void __launch_bounds__(256) k_refine(
        const float* __restrict__ xt, const float* __restrict__ sq,
        const ushort* __restrict__ knn32, int* __restrict__ idx20) {
    int wvid = (blockIdx.x << 2) + (threadIdx.x >> 6);  // wave id [0, B*N/2)
    int lane = threadIdx.x & 63;
    int half = lane >> 5;
    int sl   = lane & 31;
    int row  = (wvid << 1) + half;                      // row id [0, B*N)
    int b = row >> 12;
    int cand = knn32[(size_t)row * KSEL + sl];
    const float4* xc = (const float4*)(xt + ((size_t)(b * NPTS + cand) << 6));
    const float4* xr = (const float4*)(xt + ((size_t)row << 6));
    float acc = 0.f;
    #pragma unroll
    for (int q = 0; q < 16; ++q) {
        float4 a = xr[q], c = xc[q];
        acc = fmaf(a.x, c.x, acc); acc = fmaf(a.y, c.y, acc);
        acc = fmaf(a.z, c.z, acc); acc = fmaf(a.w, c.w, acc);
    }
    float d = fmaf(-2.f, acc, sq[b * NPTS + cand]);
    int rank = 0;
    int base = half << 5;
    #pragma unroll
    for (int j = 0; j < KSEL; ++j) {
        float dj = __shfl(d, base + j);
        int   cj = __shfl(cand, base + j);
        rank += ((dj < d) || (dj == d && cj < cand)) ? 1 : 0;
    }
    if (rank < KNN)
        idx20[(size_t)row * KNN + rank] = cand;
}

// ---------------------------------------------------------------------------
// K4: gather p columns per neighbor; per-(b,n) max/min/sum/sumsq over k;
// write tmax/tmin = (max/min_k p[idx]) + z; accumulate channel sums.
// ---------------------------------------------------------------------------
__global__ void k_gather(const float* __restrict__ pt, const float* __restrict__ zt,
                         const int* __restrict__ idxin,
                         float* __restrict__ tmax, float* __restrict__ tmin,
                         float* __restrict__ S1, float* __restrict__ S2) {
    __shared__ float red1[4][64];
    __shared__ float red2[4][64];
    int b  = blockIdx.x >> 6;
    int n0 = (blockIdx.x & 63) << 6;
    int lane = threadIdx.x & 63;
    int w = threadIdx.x >> 6;
    float cs1 = 0.f, cs2 = 0.f;
    for (int i = 0; i < 16; ++i) {
        int n = n0 + (w << 4) + i;
        int base = b * NPTS + n;
        int ibase = __builtin_amdgcn_readfirstlane(base * KNN);
        const int* ip = idxin + ibase;
        float mx = -FLT_MAX, mn = FLT_MAX, s1 = 0.f, s2 = 0.f;
        #pragma unroll
        for (int k = 0; k < KNN; ++k) {
            int colp = ip[k];                              // SGPR
            float v = pt[(((size_t)(b * NPTS + colp)) << 6) + lane]; // coalesced
            mx = fmaxf(mx, v); mn = fminf(mn, v);
            s1 += v; s2 = fmaf(v, v, s2);
        }
        float z = zt[(((size_t)base) << 6) + lane];
        tmax[(((size_t)base) << 6) + lane] = mx + z;
        tmin[(((size_t)base) << 6) + lane] = mn + z;
        cs1 += s1 + (float)KNN * z;
        cs2 += s2 + 2.f * z * s1 + (float)KNN * z * z;
    }
    red1[w][lane] = cs1;
    red2[w][lane] = cs2;
    __syncthreads();
    if (threadIdx.x < 64) {
        float t1 = red1[0][lane] + red1[1][lane] + red1[2][lane] + red1[3][lane];
        float t2 = red2[0][lane] + red2[1][lane] + red2[2][lane] + red2[3][lane];
        atomicAdd(&S1[lane], t1);
        atomicAdd(&S2[lane], t2);
    }
}

// ---------------------------------------------------------------------------
// K5: finalize BN stats, affine + LeakyReLU, transpose to out [B,64,N].
// ---------------------------------------------------------------------------
__global__ void k_final(const float* __restrict__ tmax, const float* __restrict__ tmin,
                        const float* __restrict__ S1, const float* __restrict__ S2,
                        const float* __restrict__ gamma, const float* __restrict__ beta,
                        float* __restrict__ out) {
    __shared__ float smx[64][65];
    __shared__ float smn[64][65];
    int b  = blockIdx.x >> 6;
    int n0 = (blockIdx.x & 63) << 6;
    int lane = threadIdx.x & 63;
    int w = threadIdx.x >> 6;
    #pragma unroll
    for (int i = 0; i < 16; ++i) {
        int nl = (i << 2) + w;
        size_t off = (((size_t)(b * NPTS + n0 + nl)) << 6) + lane;
        smx[nl][lane] = tmax[off];
        smn[nl][lane] = tmin[off];
    }
    __syncthreads();
    const float inv_cnt = 1.0f / ((float)BATCH * NPTS * KNN);
    #pragma unroll
    for (int i = 0; i < 16; ++i) {
        int o = (i << 2) + w;
        float s1 = S1[o], s2 = S2[o];
        float mean = s1 * inv_cnt;
        float var = fmaf(-mean, mean, s2 * inv_cnt);
        float rs = rsqrtf(var + BN_EPS);
        float sc = gamma[o] * rs;
        float sh = beta[o] - mean * sc;
        float tv = (sc >= 0.f) ? smx[lane][o] : smn[lane][o];
        float y = fmaf(tv, sc, sh);
        y = (y >= 0.f) ? y : NEG_SLOPE * y;
        out[((size_t)(b * 64 + o)) * NPTS + n0 + lane] = y;
    }
}

// ---------------------------------------------------------------------------
extern "C" void kernel_launch(void* const* d_in, const int* in_sizes, int n_in,
                              void* d_out, int out_size, void* d_ws, size_t ws_size,
                              hipStream_t stream) {
    const float* x     = (const float*)d_in[0];   // [8,64,4096]
    const float* W     = (const float*)d_in[1];   // [64,128]
    const float* gamma = (const float*)d_in[2];   // [64]
    const float* beta  = (const float*)d_in[3];   // [64]
    float* out = (float*)d_out;                   // [8,64,4096]

    float* ws = (float*)d_ws;
    const size_t SECT = (size_t)BATCH * NPTS * 64;      // 2,097,152
    float*  xt    = ws;
    float*  pt    = ws + SECT;
    float*  zt    = ws + 2 * SECT;
    float*  sq    = ws + 3 * SECT;                       // 32768
    float*  S1    = ws + 3 * SECT + 32768;               // 64
    float*  S2    = S1 + 64;
    int*    idx20 = (int*)(ws + 3 * SECT + 32768 + 128); // 655,360 ints
    float*  uA    = ws + 3 * SECT + 32768 + 128 + 655360;
    // union A:
    //   phase 1 (prep..refine): xh (SECT ushorts) | knn32 (B*N*32 ushorts)
    //   phase 2 (gather..final): tmx | tmn
    ushort* xh    = (ushort*)uA;                         // SECT ushorts
    ushort* knn32 = (ushort*)(uA + SECT / 2);            // B*N*32 ushorts
    float*  tmx   = uA;                                  // SECT floats
    float*  tmn   = uA + SECT;                           // SECT floats

    hipMemsetAsync(S1, 0, 2 * 64 * sizeof(float), stream);
    k_prep  <<<dim3((BATCH * NPTS) / 256), dim3(256), 0, stream>>>(x, xt, xh, sq);
    k_pz    <<<dim3(BATCH * (NPTS / 64)), dim3(256), 0, stream>>>(xt, W, pt, zt);
    k_knn   <<<dim3(BATCH * (NPTS / 16)), dim3(256), 0, stream>>>(xh, sq, knn32);
    k_refine<<<dim3((BATCH * NPTS) / 8), dim3(256), 0, stream>>>(xt, sq, knn32, idx20);
    k_gather<<<dim3(BATCH * (NPTS / 64)), dim3(256), 0, stream>>>(pt, zt, idx20, tmx, tmn, S1, S2);
    k_final <<<dim3(BATCH * (NPTS / 64)), dim3(256), 0, stream>>>(tmx, tmn, S1, S2, gamma, beta, out);
}

// Round 8
// 355.523 us; speedup vs baseline: 2.2723x; 2.2723x over previous
//
#include <hip/hip_runtime.h>
#include <hip/hip_bf16.h>
#include <float.h>

#define BATCH 8
#define CDIM 64
#define NPTS 4096
#define KNN 20
#define KSEL 32
#define BUFCAP 128
#define BN_EPS 1e-5f
#define NEG_SLOPE 0.2f

typedef __attribute__((ext_vector_type(8))) short short8;
typedef __attribute__((ext_vector_type(4))) float float4v;
typedef unsigned short ushort;
typedef unsigned int uint;
typedef unsigned long long ull;

__device__ __forceinline__ ushort f2bf(float f) {
    uint u = __float_as_uint(f);
    u += 0x7FFF + ((u >> 16) & 1);            // round-to-nearest-even
    return (ushort)(u >> 16);
}
__device__ __forceinline__ int mbcnt64(ull m) {
    int c = __builtin_amdgcn_mbcnt_lo((uint)m, 0);
    return __builtin_amdgcn_mbcnt_hi((uint)(m >> 32), c);
}

// Find 33rd-smallest key in buf[0..cnt), compact keys < K33 to front,
// set cnt to kept count (==32 when cnt>=33; keys distinct). Returns K33.
// Requires cnt <= 128 (two elements per lane).
__device__ __forceinline__ uint select33_truncate(uint* __restrict__ buf,
                                                  int& cnt, int lane) {
    uint e0 = 0xFFFFFFFFu, e1 = 0xFFFFFFFFu;
    if (lane < cnt) e0 = buf[lane];
    if (64 + lane < cnt) e1 = buf[64 + lane];
    uint p = 0;
    for (int bit = 31; bit >= 0; --bit) {
        uint t = p | (1u << bit);
        ull mA = __ballot(e0 < t);
        ull mB = __ballot(e1 < t);
        if (__popcll(mA) + __popcll(mB) < 33) p = t;   // uniform
    }
    ull mA = __ballot(e0 < p);
    ull mB = __ballot(e1 < p);
    int pA = __popcll(mA);
    int r0 = mbcnt64(mA);
    int r1 = pA + mbcnt64(mB);
    if (e0 < p) buf[r0] = e0;
    if (e1 < p) buf[r1] = e1;
    cnt = pA + __popcll(mB);
    return p;
}

// Streaming append of one candidate column (key = 20-bit dist | 12-bit idx).
// All control conditions are wave-uniform (ballot results / per-row scalars).
__device__ __forceinline__ void scan_append(float dwv, float base, int idx,
                                            uint& tau, int& cnt,
                                            uint* __restrict__ buf, int lane) {
    float dval = fmaxf(fmaf(-2.f, dwv, base), 0.f);
    uint key = (__float_as_uint(dval) & 0xFFFFF000u) | (uint)idx;
    ull mask = __ballot(key < tau);
    if (mask) {
        int c = __popcll(mask);
        if (cnt + c > BUFCAP) {
            tau = select33_truncate(buf, cnt, lane);
            mask = __ballot(key < tau);
            c = __popcll(mask);
        }
        if (c) {
            int rank = mbcnt64(mask);
            if (key < tau) buf[cnt + rank] = key;
            cnt += c;
        }
    }
}

// ---------------------------------------------------------------------------
// K1: x [B,C,N] -> xt [B,N,64] fp32, xh bf16, sq[b,n].
// ---------------------------------------------------------------------------
__global__ void k_prep(const float* __restrict__ x,
                       float* __restrict__ xt,
                       ushort* __restrict__ xh,
                       float* __restrict__ sq) {
    int gid = blockIdx.x * 256 + threadIdx.x;     // [0, B*N)
    int b = gid >> 12;
    int n = gid & (NPTS - 1);
    const float* xb = x + (size_t)b * CDIM * NPTS + n;
    float acc = 0.f;
    float4* xtv = (float4*)(xt + ((size_t)gid << 6));
    uint2* xhp = (uint2*)(xh + ((size_t)gid << 6));
    #pragma unroll
    for (int q = 0; q < 16; ++q) {
        float v[4]; ushort h[4];
        #pragma unroll
        for (int j = 0; j < 4; ++j) {
            float tv = xb[(q * 4 + j) * NPTS];    // coalesced across n
            v[j] = tv;
            acc = fmaf(tv, tv, acc);
            h[j] = f2bf(tv);
        }
        xtv[q] = make_float4(v[0], v[1], v[2], v[3]);
        uint2 ph;
        ph.x = (uint)h[0] | ((uint)h[1] << 16);
        ph.y = (uint)h[2] | ((uint)h[3] << 16);
        xhp[q] = ph;
    }
    sq[gid] = acc;
}

// ---------------------------------------------------------------------------
// K2: p = W1 @ x, z = (W2-W1) @ x, stored transposed: pt/zt [B,N,64]
// ---------------------------------------------------------------------------
__global__ void k_pz(const float* __restrict__ xt, const float* __restrict__ W,
                     float* __restrict__ pt, float* __restrict__ zt) {
    int b  = blockIdx.x >> 6;
    int n0 = (blockIdx.x & 63) << 6;
    int lane = threadIdx.x & 63;
    int w = threadIdx.x >> 6;
    int n = n0 + lane;
    size_t rowoff = ((size_t)(b * NPTS + n)) << 6;
    const float4* xrow = (const float4*)(xt + rowoff);
    float acc1[16], acc2[16];
    #pragma unroll
    for (int i = 0; i < 16; ++i) { acc1[i] = 0.f; acc2[i] = 0.f; }
    #pragma unroll
    for (int cg = 0; cg < 4; ++cg) {
        float xv[16];
        #pragma unroll
        for (int q = 0; q < 4; ++q) {
            float4 t = xrow[cg * 4 + q];
            xv[q*4] = t.x; xv[q*4+1] = t.y; xv[q*4+2] = t.z; xv[q*4+3] = t.w;
        }
        #pragma unroll
        for (int oi = 0; oi < 16; ++oi) {
            int o = (w << 4) + oi;
            const float* wr = W + o * 128 + cg * 16;
            float a1 = acc1[oi], a2 = acc2[oi];
            #pragma unroll
            for (int j = 0; j < 16; ++j) {
                a1 = fmaf(wr[j],      xv[j], a1);
                a2 = fmaf(wr[64 + j], xv[j], a2);
            }
            acc1[oi] = a1; acc2[oi] = a2;
        }
    }
    float4* pv = (float4*)(pt + rowoff + (w << 4));
    float4* zv = (float4*)(zt + rowoff + (w << 4));
    #pragma unroll
    for (int q = 0; q < 4; ++q) {
        pv[q] = make_float4(acc1[q*4], acc1[q*4+1], acc1[q*4+2], acc1[q*4+3]);
        zv[q] = make_float4(acc2[q*4]   - acc1[q*4],
                            acc2[q*4+1] - acc1[q*4+1],
                            acc2[q*4+2] - acc1[q*4+2],
                            acc2[q*4+3] - acc1[q*4+3]);
    }
}

// ---------------------------------------------------------------------------
// K3: R3 structure, convoy halved — 4-wave blocks own 16 rows. Single-bf16
// MFMA kNN, no LDS staging (B-frags direct from L2-resident 512 KB xh slice,
// register ping-pong one chunk ahead). dw parity double-buffer in LDS; wave
// t computes cands [16t,16t+16) x 16 rows, scans rows [4t,4t+4) of chunk
// c-1. Barrier is raw s_barrier + lgkmcnt(0) only (global loads stay in
// flight across it). vs R3 (8-wave blocks): per-interval time is max over 4
// waves, not 8 (select spikes hurt half as often), and LDS 16.9 KB with
// grid 2048x256 = exactly 8 blocks/CU -> full occupancy, zero tail.
// Hazard ledger (each pair separated by exactly one barrier):
//   dw[q] write @c     vs dw[q] scan  @c+1
//   dw[q^1] scan @c    vs dw[q^1] write @c+1
// ---------------------------------------------------------------------------
__global__ void __launch_bounds__(256, 8) k_knn(
        const ushort* __restrict__ xh,
        const float* __restrict__ sq, ushort* __restrict__ knn32) {
    __shared__ float dw[2][16][68];       // parity dist tiles, 8.7 KB
    __shared__ uint rowbuf[16 * BUFCAP];  // 4 waves x 4 rows x 128, 8.2 KB

    int tid  = threadIdx.x;
    int t    = tid >> 6;              // wave 0..3
    int lane = tid & 63;
    int b    = blockIdx.x >> 8;       // 256 blocks per batch
    int r0   = (blockIdx.x & 255) << 4;   // block's 16 rows
    int col  = lane & 15;
    int quad = lane >> 4;

    // A fragments (chunk-invariant): row = r0 + col, k = quad*8 + j
    size_t arow = ((size_t)(b * NPTS + r0 + col)) << 6;
    short8 ah0 = *(const short8*)(xh + arow + quad * 8);
    short8 ah1 = *(const short8*)(xh + arow + 32 + quad * 8);

    const ushort* xhb = xh + (((size_t)b * NPTS) << 6);
    const float* sqb = sq + b * NPTS;
    // B-frag base for this lane: point (t*16+col) of chunk 0
    const ushort* fbase = xhb + (((size_t)((t << 4) + col)) << 6) + (quad << 3);

    uint tau[4];
    int cnt[4];
    float sqr[4];
    uint* wbuf = rowbuf + ((t << 2) * BUFCAP);
    #pragma unroll
    for (int r = 0; r < 4; ++r) {
        tau[r] = 0xFFFFFFFFu; cnt[r] = 0;
        sqr[r] = sqb[r0 + (t << 2) + r];
    }

    // prologue: frags + candidate-sq for chunk 0
    short8 fA0 = *(const short8*)fbase;
    short8 fA1 = *(const short8*)(fbase + 32);
    short8 fB0, fB1;
    float sv_cur = 0.f;               // sq of chunk (c-1) candidates at lane
    float sv_nxt = sqb[lane];         // sq of chunk c candidates at lane

    auto step = [&](int c, int q, short8& f0, short8& f1,
                    short8& nf0, short8& nf1) {
        // issue next-chunk frag + sq loads early (stay in flight over barrier)
        if (c + 1 < 64) {
            const ushort* p = fbase + (((size_t)(c + 1)) << 12);
            nf0 = *(const short8*)p;
            nf1 = *(const short8*)(p + 32);
        }
        float sv_tmp = (c + 1 < 64) ? sqb[((c + 1) << 6) + lane] : 0.f;

        // MFMA for chunk c: cands [16t,16t+16), rows [r0,r0+16)
        float4v acc = {0.f, 0.f, 0.f, 0.f};
        acc = __builtin_amdgcn_mfma_f32_16x16x32_bf16(ah0, f0, acc, 0, 0, 0);
        acc = __builtin_amdgcn_mfma_f32_16x16x32_bf16(ah1, f1, acc, 0, 0, 0);
        #pragma unroll
        for (int r = 0; r < 4; ++r)
            dw[q][(quad << 2) + r][(t << 4) + col] = acc[r];

        // scan chunk c-1 (dw parity q^1); lane = candidate
        if (c > 0) {
            int m0 = (c - 1) << 6;
            #pragma unroll
            for (int r = 0; r < 4; ++r) {
                float dv = dw[q ^ 1][(t << 2) + r][lane];
                scan_append(dv, sv_cur + sqr[r], m0 + lane, tau[r], cnt[r],
                            wbuf + r * BUFCAP, lane);
            }
        }
        sv_cur = sv_nxt;
        sv_nxt = sv_tmp;

        // raw barrier: order LDS (dw, rowbuf) only; vmem stays in flight
        __builtin_amdgcn_sched_barrier(0);
        asm volatile("s_waitcnt lgkmcnt(0)" ::: "memory");
        __builtin_amdgcn_s_barrier();
        __builtin_amdgcn_sched_barrier(0);
    };

    for (int c = 0; c < 64; c += 2) {
        step(c,     0, fA0, fA1, fB0, fB1);
        step(c + 1, 1, fB0, fB1, fA0, fA1);
    }

    // drain: scan chunk 63 (dw parity 1); loop's final barrier ordered it
    {
        int m0 = 63 << 6;
        #pragma unroll
        for (int r = 0; r < 4; ++r) {
            float dv = dw[1][(t << 2) + r][lane];
            scan_append(dv, sv_cur + sqr[r], m0 + lane, tau[r], cnt[r],
                        wbuf + r * BUFCAP, lane);
        }
    }

    // final extraction: exact key-top-32 per row
    #pragma unroll
    for (int r = 0; r < 4; ++r) {
        select33_truncate(wbuf + r * BUFCAP, cnt[r], lane);
        if (lane < KSEL) {
            uint e = wbuf[r * BUFCAP + lane];
            knn32[(size_t)(b * NPTS + r0 + (t << 2) + r) * KSEL + lane] =
                (ushort)(e & 0xFFFu);
        }
    }
}

// ---------------------------------------------------------------------------
// K3b: exact fp32 refinement — TWO rows per wave (half-wave per row, no idle
// lanes): 32 candidates in each half's lanes, exact fp32 distances, rank
// lexicographically (dist, idx) per np tie rule, emit top-20 set.
// ---------------------------------------------------------------------------
__global__ void __launch_bounds__(256) k_refine(
        const float* __restrict__ xt, const float* __restrict__ sq,
        const ushort* __restrict__ knn32, int* __restrict__ idx20) {
    int wvid = (blockIdx.x << 2) + (threadIdx.x >> 6);  // wave id [0, B*N/2)
    int lane = threadIdx.x & 63;
    int half = lane >> 5;
    int sl   = lane & 31;
    int row  = (wvid << 1) + half;                      // row id [0, B*N)
    int b = row >> 12;
    int cand = knn32[(size_t)row * KSEL + sl];
    const float4* xc = (const float4*)(xt + ((size_t)(b * NPTS + cand) << 6));
    const float4* xr = (const float4*)(xt + ((size_t)row << 6));
    float acc = 0.f;
    #pragma unroll
    for (int q = 0; q < 16; ++q) {
        float4 a = xr[q], c = xc[q];
        acc = fmaf(a.x, c.x, acc); acc = fmaf(a.y, c.y, acc);
        acc = fmaf(a.z, c.z, acc); acc = fmaf(a.w, c.w, acc);
    }
    float d = fmaf(-2.f, acc, sq[b * NPTS + cand]);
    int rank = 0;
    int base = half << 5;
    #pragma unroll
    for (int j = 0; j < KSEL; ++j) {
        float dj = __shfl(d, base + j);
        int   cj = __shfl(cand, base + j);
        rank += ((dj < d) || (dj == d && cj < cand)) ? 1 : 0;
    }
    if (rank < KNN)
        idx20[(size_t)row * KNN + rank] = cand;
}

// ---------------------------------------------------------------------------
// K4: gather p columns per neighbor; per-(b,n) max/min/sum/sumsq over k;
// write tmax/tmin = (max/min_k p[idx]) + z; accumulate channel sums.
// ---------------------------------------------------------------------------
__global__ void k_gather(const float* __restrict__ pt, const float* __restrict__ zt,
                         const int* __restrict__ idxin,
                         float* __restrict__ tmax, float* __restrict__ tmin,
                         float* __restrict__ S1, float* __restrict__ S2) {
    __shared__ float red1[4][64];
    __shared__ float red2[4][64];
    int b  = blockIdx.x >> 6;
    int n0 = (blockIdx.x & 63) << 6;
    int lane = threadIdx.x & 63;
    int w = threadIdx.x >> 6;
    float cs1 = 0.f, cs2 = 0.f;
    for (int i = 0; i < 16; ++i) {
        int n = n0 + (w << 4) + i;
        int base = b * NPTS + n;
        int ibase = __builtin_amdgcn_readfirstlane(base * KNN);
        const int* ip = idxin + ibase;
        float mx = -FLT_MAX, mn = FLT_MAX, s1 = 0.f, s2 = 0.f;
        #pragma unroll
        for (int k = 0; k < KNN; ++k) {
            int colp = ip[k];                              // SGPR
            float v = pt[(((size_t)(b * NPTS + colp)) << 6) + lane]; // coalesced
            mx = fmaxf(mx, v); mn = fminf(mn, v);
            s1 += v; s2 = fmaf(v, v, s2);
        }
        float z = zt[(((size_t)base) << 6) + lane];
        tmax[(((size_t)base) << 6) + lane] = mx + z;
        tmin[(((size_t)base) << 6) + lane] = mn + z;
        cs1 += s1 + (float)KNN * z;
        cs2 += s2 + 2.f * z * s1 + (float)KNN * z * z;
    }
    red1[w][lane] = cs1;
    red2[w][lane] = cs2;
    __syncthreads();
    if (threadIdx.x < 64) {
        float t1 = red1[0][lane] + red1[1][lane] + red1[2][lane] + red1[3][lane];
        float t2 = red2[0][lane] + red2[1][lane] + red2[2][lane] + red2[3][lane];
        atomicAdd(&S1[lane], t1);
        atomicAdd(&S2[lane], t2);
    }
}

// ---------------------------------------------------------------------------
// K5: finalize BN stats, affine + LeakyReLU, transpose to out [B,64,N].
// ---------------------------------------------------------------------------
__global__ void k_final(const float* __restrict__ tmax, const float* __restrict__ tmin,
                        const float* __restrict__ S1, const float* __restrict__ S2,
                        const float* __restrict__ gamma, const float* __restrict__ beta,
                        float* __restrict__ out) {
    __shared__ float smx[64][65];
    __shared__ float smn[64][65];
    int b  = blockIdx.x >> 6;
    int n0 = (blockIdx.x & 63) << 6;
    int lane = threadIdx.x & 63;
    int w = threadIdx.x >> 6;
    #pragma unroll
    for (int i = 0; i < 16; ++i) {
        int nl = (i << 2) + w;
        size_t off = (((size_t)(b * NPTS + n0 + nl)) << 6) + lane;
        smx[nl][lane] = tmax[off];
        smn[nl][lane] = tmin[off];
    }
    __syncthreads();
    const float inv_cnt = 1.0f / ((float)BATCH * NPTS * KNN);
    #pragma unroll
    for (int i = 0; i < 16; ++i) {
        int o = (i << 2) + w;
        float s1 = S1[o], s2 = S2[o];
        float mean = s1 * inv_cnt;
        float var = fmaf(-mean, mean, s2 * inv_cnt);
        float rs = rsqrtf(var + BN_EPS);
        float sc = gamma[o] * rs;
        float sh = beta[o] - mean * sc;
        float tv = (sc >= 0.f) ? smx[lane][o] : smn[lane][o];
        float y = fmaf(tv, sc, sh);
        y = (y >= 0.f) ? y : NEG_SLOPE * y;
        out[((size_t)(b * 64 + o)) * NPTS + n0 + lane] = y;
    }
}

// ---------------------------------------------------------------------------
extern "C" void kernel_launch(void* const* d_in, const int* in_sizes, int n_in,
                              void* d_out, int out_size, void* d_ws, size_t ws_size,
                              hipStream_t stream) {
    const float* x     = (const float*)d_in[0];   // [8,64,4096]
    const float* W     = (const float*)d_in[1];   // [64,128]
    const float* gamma = (const float*)d_in[2];   // [64]
    const float* beta  = (const float*)d_in[3];   // [64]
    float* out = (float*)d_out;                   // [8,64,4096]

    float* ws = (float*)d_ws;
    const size_t SECT = (size_t)BATCH * NPTS * 64;      // 2,097,152
    float*  xt    = ws;
    float*  pt    = ws + SECT;
    float*  zt    = ws + 2 * SECT;
    float*  sq    = ws + 3 * SECT;                       // 32768
    float*  S1    = ws + 3 * SECT + 32768;               // 64
    float*  S2    = S1 + 64;
    int*    idx20 = (int*)(ws + 3 * SECT + 32768 + 128); // 655,360 ints
    float*  uA    = ws + 3 * SECT + 32768 + 128 + 655360;
    // union A:
    //   phase 1 (prep..refine): xh (SECT ushorts) | knn32 (B*N*32 ushorts)
    //   phase 2 (gather..final): tmx | tmn
    ushort* xh    = (ushort*)uA;                         // SECT ushorts
    ushort* knn32 = (ushort*)(uA + SECT / 2);            // B*N*32 ushorts
    float*  tmx   = uA;                                  // SECT floats
    float*  tmn   = uA + SECT;                           // SECT floats

    hipMemsetAsync(S1, 0, 2 * 64 * sizeof(float), stream);
    k_prep  <<<dim3((BATCH * NPTS) / 256), dim3(256), 0, stream>>>(x, xt, xh, sq);
    k_pz    <<<dim3(BATCH * (NPTS / 64)), dim3(256), 0, stream>>>(xt, W, pt, zt);
    k_knn   <<<dim3(BATCH * (NPTS / 16)), dim3(256), 0, stream>>>(xh, sq, knn32);
    k_refine<<<dim3((BATCH * NPTS) / 8), dim3(256), 0, stream>>>(xt, sq, knn32, idx20);
    k_gather<<<dim3(BATCH * (NPTS / 64)), dim3(256), 0, stream>>>(pt, zt, idx20, tmx, tmn, S1, S2);
    k_final <<<dim3(BATCH * (NPTS / 64)), dim3(256), 0, stream>>>(tmx, tmn, S1, S2, gamma, beta, out);
}

// Round 9
// 328.407 us; speedup vs baseline: 2.4600x; 1.0826x over previous
//
#include <hip/hip_runtime.h>
#include <hip/hip_bf16.h>
#include <float.h>

#define BATCH 8
#define CDIM 64
#define NPTS 4096
#define KNN 20
#define KSEL 32
#define BUFCAP 128
#define BN_EPS 1e-5f
#define NEG_SLOPE 0.2f

typedef __attribute__((ext_vector_type(8))) short short8;
typedef __attribute__((ext_vector_type(4))) float float4v;
typedef unsigned short ushort;
typedef unsigned int uint;
typedef unsigned long long ull;

__device__ __forceinline__ ushort f2bf(float f) {
    uint u = __float_as_uint(f);
    u += 0x7FFF + ((u >> 16) & 1);            // round-to-nearest-even
    return (ushort)(u >> 16);
}
__device__ __forceinline__ int mbcnt64(ull m) {
    int c = __builtin_amdgcn_mbcnt_lo((uint)m, 0);
    return __builtin_amdgcn_mbcnt_hi((uint)(m >> 32), c);
}

// Find 33rd-smallest key in buf[0..cnt), compact keys < K33 to front,
// set cnt to kept count (==32 when cnt>=33; keys distinct). Returns K33.
// Requires cnt <= 128 (two elements per lane).
__device__ __forceinline__ uint select33_truncate(uint* __restrict__ buf,
                                                  int& cnt, int lane) {
    uint e0 = 0xFFFFFFFFu, e1 = 0xFFFFFFFFu;
    if (lane < cnt) e0 = buf[lane];
    if (64 + lane < cnt) e1 = buf[64 + lane];
    uint p = 0;
    for (int bit = 31; bit >= 0; --bit) {
        uint t = p | (1u << bit);
        ull mA = __ballot(e0 < t);
        ull mB = __ballot(e1 < t);
        if (__popcll(mA) + __popcll(mB) < 33) p = t;   // uniform
    }
    ull mA = __ballot(e0 < p);
    ull mB = __ballot(e1 < p);
    int pA = __popcll(mA);
    int r0 = mbcnt64(mA);
    int r1 = pA + mbcnt64(mB);
    if (e0 < p) buf[r0] = e0;
    if (e1 < p) buf[r1] = e1;
    cnt = pA + __popcll(mB);
    return p;
}

// Streaming append of one candidate column (key = 20-bit dist | 12-bit idx).
// All control conditions are wave-uniform (ballot results / per-row scalars).
__device__ __forceinline__ void scan_append(float dwv, float base, int idx,
                                            uint& tau, int& cnt,
                                            uint* __restrict__ buf, int lane) {
    float dval = fmaxf(fmaf(-2.f, dwv, base), 0.f);
    uint key = (__float_as_uint(dval) & 0xFFFFF000u) | (uint)idx;
    ull mask = __ballot(key < tau);
    if (mask) {
        int c = __popcll(mask);
        if (cnt + c > BUFCAP) {
            tau = select33_truncate(buf, cnt, lane);
            mask = __ballot(key < tau);
            c = __popcll(mask);
        }
        if (c) {
            int rank = mbcnt64(mask);
            if (key < tau) buf[cnt + rank] = key;
            cnt += c;
        }
    }
}

// ---------------------------------------------------------------------------
// K1: fused prep+pz. Block = 256 thr (4 waves) owns batch b, points
// n0..n0+64. Phase 1: thread (w,lane) loads channels w*16..w*16+16 of point
// n0+lane (coalesced across lane), computes partial sq, bf16-converts,
// stages the fp32 tile in LDS xs[n_local][c] (pad 65: bank (lane+c)%32,
// 2-way = free), writes xt/xh to global (needed by knn/refine). Phase 2
// (after the one barrier): the W-matmul reads x straight from LDS —
// eliminates the 8 MB xt global re-read and one kernel launch.
// ---------------------------------------------------------------------------
__global__ void __launch_bounds__(256) k_ppz(
        const float* __restrict__ x, const float* __restrict__ W,
        float* __restrict__ xt, ushort* __restrict__ xh,
        float* __restrict__ sq,
        float* __restrict__ pt, float* __restrict__ zt) {
    __shared__ float xs[64][65];      // [n_local][channel]
    __shared__ float sqred[4][64];

    int b  = blockIdx.x >> 6;
    int n0 = (blockIdx.x & 63) << 6;
    int lane = threadIdx.x & 63;
    int w = threadIdx.x >> 6;
    int row = b * NPTS + n0 + lane;

    // phase 1: prep for point n0+lane, channels [16w, 16w+16)
    const float* xb = x + (size_t)b * CDIM * NPTS + (n0 + lane);
    float v[16]; ushort h[16];
    float accq = 0.f;
    #pragma unroll
    for (int j = 0; j < 16; ++j) {
        float tv = xb[((w << 4) + j) * NPTS];   // coalesced across lane
        v[j] = tv;
        accq = fmaf(tv, tv, accq);
        h[j] = f2bf(tv);
        xs[lane][(w << 4) + j] = tv;
    }
    {
        float4* xtv = (float4*)(xt + ((size_t)row << 6) + (w << 4));
        #pragma unroll
        for (int q = 0; q < 4; ++q)
            xtv[q] = make_float4(v[q*4], v[q*4+1], v[q*4+2], v[q*4+3]);
        uint4* xhp = (uint4*)(xh + ((size_t)row << 6) + (w << 4));
        uint4 p0, p1;
        p0.x = (uint)h[0] | ((uint)h[1] << 16);
        p0.y = (uint)h[2] | ((uint)h[3] << 16);
        p0.z = (uint)h[4] | ((uint)h[5] << 16);
        p0.w = (uint)h[6] | ((uint)h[7] << 16);
        p1.x = (uint)h[8] | ((uint)h[9] << 16);
        p1.y = (uint)h[10] | ((uint)h[11] << 16);
        p1.z = (uint)h[12] | ((uint)h[13] << 16);
        p1.w = (uint)h[14] | ((uint)h[15] << 16);
        xhp[0] = p0; xhp[1] = p1;
    }
    sqred[w][lane] = accq;
    __syncthreads();
    if (w == 0)
        sq[row] = sqred[0][lane] + sqred[1][lane] +
                  sqred[2][lane] + sqred[3][lane];

    // phase 2: pz from the LDS tile (reads: all lanes same c -> 2-way free)
    size_t rowoff = ((size_t)row) << 6;
    float acc1[16], acc2[16];
    #pragma unroll
    for (int i = 0; i < 16; ++i) { acc1[i] = 0.f; acc2[i] = 0.f; }
    #pragma unroll
    for (int cg = 0; cg < 4; ++cg) {
        float xv[16];
        #pragma unroll
        for (int j = 0; j < 16; ++j)
            xv[j] = xs[lane][(cg << 4) + j];
        #pragma unroll
        for (int oi = 0; oi < 16; ++oi) {
            int o = (w << 4) + oi;
            const float* wr = W + o * 128 + cg * 16;
            float a1 = acc1[oi], a2 = acc2[oi];
            #pragma unroll
            for (int j = 0; j < 16; ++j) {
                a1 = fmaf(wr[j],      xv[j], a1);
                a2 = fmaf(wr[64 + j], xv[j], a2);
            }
            acc1[oi] = a1; acc2[oi] = a2;
        }
    }
    float4* pv = (float4*)(pt + rowoff + (w << 4));
    float4* zv = (float4*)(zt + rowoff + (w << 4));
    #pragma unroll
    for (int q = 0; q < 4; ++q) {
        pv[q] = make_float4(acc1[q*4], acc1[q*4+1], acc1[q*4+2], acc1[q*4+3]);
        zv[q] = make_float4(acc2[q*4]   - acc1[q*4],
                            acc2[q*4+1] - acc1[q*4+1],
                            acc2[q*4+2] - acc1[q*4+2],
                            acc2[q*4+3] - acc1[q*4+3]);
    }
}

// ---------------------------------------------------------------------------
// K3: R8 structure with TRANSPOSED dw -> b128 LDS exchange.
// dw[parity][cand][row-stride-20]: acc[0..3] (4 consecutive rows of one
// cand, per m89 C/D layout) store as ONE ds_write_b128; scan reads rows
// [4t,4t+4) at cand=lane as ONE ds_read_b128. LDS ops per wave-interval
// drop 12 -> 3 (the measured VALU+LDS joint issue bound). Stride 20 floats
// keeps 16-B alignment (80 B rows) and uniform b128 start-banks
// (4*(5c+q) mod 32 covers all 8 residues evenly, both directions).
// Everything else identical to R8 (4-wave blocks, 16 rows, lgkmcnt-only
// barrier, ping-pong frags from L2, BUFCAP 128).
// Hazard ledger (each pair separated by exactly one barrier):
//   dw[q] write @c     vs dw[q] scan  @c+1
//   dw[q^1] scan @c    vs dw[q^1] write @c+1
// ---------------------------------------------------------------------------
__global__ void __launch_bounds__(256, 8) k_knn(
        const ushort* __restrict__ xh,
        const float* __restrict__ sq, ushort* __restrict__ knn32) {
    __shared__ float dw[2][64][20];       // [parity][cand][rows 0..15], 10 KB
    __shared__ uint rowbuf[16 * BUFCAP];  // 4 waves x 4 rows x 128, 8.2 KB

    int tid  = threadIdx.x;
    int t    = tid >> 6;              // wave 0..3
    int lane = tid & 63;
    int b    = blockIdx.x >> 8;       // 256 blocks per batch
    int r0   = (blockIdx.x & 255) << 4;   // block's 16 rows
    int col  = lane & 15;
    int quad = lane >> 4;

    // A fragments (chunk-invariant): row = r0 + col, k = quad*8 + j
    size_t arow = ((size_t)(b * NPTS + r0 + col)) << 6;
    short8 ah0 = *(const short8*)(xh + arow + quad * 8);
    short8 ah1 = *(const short8*)(xh + arow + 32 + quad * 8);

    const ushort* xhb = xh + (((size_t)b * NPTS) << 6);
    const float* sqb = sq + b * NPTS;
    // B-frag base for this lane: point (t*16+col) of chunk 0
    const ushort* fbase = xhb + (((size_t)((t << 4) + col)) << 6) + (quad << 3);

    uint tau[4];
    int cnt[4];
    float sqr[4];
    uint* wbuf = rowbuf + ((t << 2) * BUFCAP);
    #pragma unroll
    for (int r = 0; r < 4; ++r) {
        tau[r] = 0xFFFFFFFFu; cnt[r] = 0;
        sqr[r] = sqb[r0 + (t << 2) + r];
    }

    // prologue: frags + candidate-sq for chunk 0
    short8 fA0 = *(const short8*)fbase;
    short8 fA1 = *(const short8*)(fbase + 32);
    short8 fB0, fB1;
    float sv_cur = 0.f;               // sq of chunk (c-1) candidates at lane
    float sv_nxt = sqb[lane];         // sq of chunk c candidates at lane

    auto step = [&](int c, int q, short8& f0, short8& f1,
                    short8& nf0, short8& nf1) {
        // issue next-chunk frag + sq loads early (stay in flight over barrier)
        if (c + 1 < 64) {
            const ushort* p = fbase + (((size_t)(c + 1)) << 12);
            nf0 = *(const short8*)p;
            nf1 = *(const short8*)(p + 32);
        }
        float sv_tmp = (c + 1 < 64) ? sqb[((c + 1) << 6) + lane] : 0.f;

        // MFMA for chunk c: cands [16t,16t+16), rows [r0,r0+16)
        float4v acc = {0.f, 0.f, 0.f, 0.f};
        acc = __builtin_amdgcn_mfma_f32_16x16x32_bf16(ah0, f0, acc, 0, 0, 0);
        acc = __builtin_amdgcn_mfma_f32_16x16x32_bf16(ah1, f1, acc, 0, 0, 0);
        // acc[r] = dist(row 4*quad+r, cand 16t+col): 4 consecutive rows of
        // one cand -> single b128 store (16-B aligned: 80*(16t+col)+16q)
        *(float4v*)&dw[q][(t << 4) + col][quad << 2] = acc;

        // scan chunk c-1 (dw parity q^1): one b128 read gives this wave's
        // 4 rows for cand=lane
        if (c > 0) {
            int m0 = (c - 1) << 6;
            float4v dv4 = *(const float4v*)&dw[q ^ 1][lane][t << 2];
            #pragma unroll
            for (int r = 0; r < 4; ++r) {
                scan_append(dv4[r], sv_cur + sqr[r], m0 + lane, tau[r], cnt[r],
                            wbuf + r * BUFCAP, lane);
            }
        }
        sv_cur = sv_nxt;
        sv_nxt = sv_tmp;

        // raw barrier: order LDS (dw, rowbuf) only; vmem stays in flight
        __builtin_amdgcn_sched_barrier(0);
        asm volatile("s_waitcnt lgkmcnt(0)" ::: "memory");
        __builtin_amdgcn_s_barrier();
        __builtin_amdgcn_sched_barrier(0);
    };

    for (int c = 0; c < 64; c += 2) {
        step(c,     0, fA0, fA1, fB0, fB1);
        step(c + 1, 1, fB0, fB1, fA0, fA1);
    }

    // drain: scan chunk 63 (dw parity 1); loop's final barrier ordered it
    {
        int m0 = 63 << 6;
        float4v dv4 = *(const float4v*)&dw[1][lane][t << 2];
        #pragma unroll
        for (int r = 0; r < 4; ++r) {
            scan_append(dv4[r], sv_cur + sqr[r], m0 + lane, tau[r], cnt[r],
                        wbuf + r * BUFCAP, lane);
        }
    }

    // final extraction: exact key-top-32 per row
    #pragma unroll
    for (int r = 0; r < 4; ++r) {
        select33_truncate(wbuf + r * BUFCAP, cnt[r], lane);
        if (lane < KSEL) {
            uint e = wbuf[r * BUFCAP + lane];
            knn32[(size_t)(b * NPTS + r0 + (t << 2) + r) * KSEL + lane] =
                (ushort)(e & 0xFFFu);
        }
    }
}

// ---------------------------------------------------------------------------
// K3b: exact fp32 refinement — TWO rows per wave (half-wave per row, no idle
// lanes): 32 candidates in each half's lanes, exact fp32 distances, rank
// lexicographically (dist, idx) per np tie rule, emit top-20 set.
// ---------------------------------------------------------------------------
__global__ void __launch_bounds__(256) k_refine(
        const float* __restrict__ xt, const float* __restrict__ sq,
        const ushort* __restrict__ knn32, int* __restrict__ idx20) {
    int wvid = (blockIdx.x << 2) + (threadIdx.x >> 6);  // wave id [0, B*N/2)
    int lane = threadIdx.x & 63;
    int half = lane >> 5;
    int sl   = lane & 31;
    int row  = (wvid << 1) + half;                      // row id [0, B*N)
    int b = row >> 12;
    int cand = knn32[(size_t)row * KSEL + sl];
    const float4* xc = (const float4*)(xt + ((size_t)(b * NPTS + cand) << 6));
    const float4* xr = (const float4*)(xt + ((size_t)row << 6));
    float acc = 0.f;
    #pragma unroll
    for (int q = 0; q < 16; ++q) {
        float4 a = xr[q], c = xc[q];
        acc = fmaf(a.x, c.x, acc); acc = fmaf(a.y, c.y, acc);
        acc = fmaf(a.z, c.z, acc); acc = fmaf(a.w, c.w, acc);
    }
    float d = fmaf(-2.f, acc, sq[b * NPTS + cand]);
    int rank = 0;
    int base = half << 5;
    #pragma unroll
    for (int j = 0; j < KSEL; ++j) {
        float dj = __shfl(d, base + j);
        int   cj = __shfl(cand, base + j);
        rank += ((dj < d) || (dj == d && cj < cand)) ? 1 : 0;
    }
    if (rank < KNN)
        idx20[(size_t)row * KNN + rank] = cand;
}

// ---------------------------------------------------------------------------
// K4: gather p columns per neighbor; per-(b,n) max/min/sum/sumsq over k;
// write tmax/tmin = (max/min_k p[idx]) + z; accumulate channel sums.
// ---------------------------------------------------------------------------
__global__ void k_gather(const float* __restrict__ pt, const float* __restrict__ zt,
                         const int* __restrict__ idxin,
                         float* __restrict__ tmax, float* __restrict__ tmin,
                         float* __restrict__ S1, float* __restrict__ S2) {
    __shared__ float red1[4][64];
    __shared__ float red2[4][64];
    int b  = blockIdx.x >> 6;
    int n0 = (blockIdx.x & 63) << 6;
    int lane = threadIdx.x & 63;
    int w = threadIdx.x >> 6;
    float cs1 = 0.f, cs2 = 0.f;
    for (int i = 0; i < 16; ++i) {
        int n = n0 + (w << 4) + i;
        int base = b * NPTS + n;
        int ibase = __builtin_amdgcn_readfirstlane(base * KNN);
        const int* ip = idxin + ibase;
        float mx = -FLT_MAX, mn = FLT_MAX, s1 = 0.f, s2 = 0.f;
        #pragma unroll
        for (int k = 0; k < KNN; ++k) {
            int colp = ip[k];                              // SGPR
            float v = pt[(((size_t)(b * NPTS + colp)) << 6) + lane]; // coalesced
            mx = fmaxf(mx, v); mn = fminf(mn, v);
            s1 += v; s2 = fmaf(v, v, s2);
        }
        float z = zt[(((size_t)base) << 6) + lane];
        tmax[(((size_t)base) << 6) + lane] = mx + z;
        tmin[(((size_t)base) << 6) + lane] = mn + z;
        cs1 += s1 + (float)KNN * z;
        cs2 += s2 + 2.f * z * s1 + (float)KNN * z * z;
    }
    red1[w][lane] = cs1;
    red2[w][lane] = cs2;
    __syncthreads();
    if (threadIdx.x < 64) {
        float t1 = red1[0][lane] + red1[1][lane] + red1[2][lane] + red1[3][lane];
        float t2 = red2[0][lane] + red2[1][lane] + red2[2][lane] + red2[3][lane];
        atomicAdd(&S1[lane], t1);
        atomicAdd(&S2[lane], t2);
    }
}

// ---------------------------------------------------------------------------
// K5: finalize BN stats, affine + LeakyReLU, transpose to out [B,64,N].
// ---------------------------------------------------------------------------
__global__ void k_final(const float* __restrict__ tmax, const float* __restrict__ tmin,
                        const float* __restrict__ S1, const float* __restrict__ S2,
                        const float* __restrict__ gamma, const float* __restrict__ beta,
                        float* __restrict__ out) {
    __shared__ float smx[64][65];
    __shared__ float smn[64][65];
    int b  = blockIdx.x >> 6;
    int n0 = (blockIdx.x & 63) << 6;
    int lane = threadIdx.x & 63;
    int w = threadIdx.x >> 6;
    #pragma unroll
    for (int i = 0; i < 16; ++i) {
        int nl = (i << 2) + w;
        size_t off = (((size_t)(b * NPTS + n0 + nl)) << 6) + lane;
        smx[nl][lane] = tmax[off];
        smn[nl][lane] = tmin[off];
    }
    __syncthreads();
    const float inv_cnt = 1.0f / ((float)BATCH * NPTS * KNN);
    #pragma unroll
    for (int i = 0; i < 16; ++i) {
        int o = (i << 2) + w;
        float s1 = S1[o], s2 = S2[o];
        float mean = s1 * inv_cnt;
        float var = fmaf(-mean, mean, s2 * inv_cnt);
        float rs = rsqrtf(var + BN_EPS);
        float sc = gamma[o] * rs;
        float sh = beta[o] - mean * sc;
        float tv = (sc >= 0.f) ? smx[lane][o] : smn[lane][o];
        float y = fmaf(tv, sc, sh);
        y = (y >= 0.f) ? y : NEG_SLOPE * y;
        out[((size_t)(b * 64 + o)) * NPTS + n0 + lane] = y;
    }
}

// ---------------------------------------------------------------------------
extern "C" void kernel_launch(void* const* d_in, const int* in_sizes, int n_in,
                              void* d_out, int out_size, void* d_ws, size_t ws_size,
                              hipStream_t stream) {
    const float* x     = (const float*)d_in[0];   // [8,64,4096]
    const float* W     = (const float*)d_in[1];   // [64,128]
    const float* gamma = (const float*)d_in[2];   // [64]
    const float* beta  = (const float*)d_in[3];   // [64]
    float* out = (float*)d_out;                   // [8,64,4096]

    float* ws = (float*)d_ws;
    const size_t SECT = (size_t)BATCH * NPTS * 64;      // 2,097,152
    float*  xt    = ws;
    float*  pt    = ws + SECT;
    float*  zt    = ws + 2 * SECT;
    float*  sq    = ws + 3 * SECT;                       // 32768
    float*  S1    = ws + 3 * SECT + 32768;               // 64
    float*  S2    = S1 + 64;
    int*    idx20 = (int*)(ws + 3 * SECT + 32768 + 128); // 655,360 ints
    float*  uA    = ws + 3 * SECT + 32768 + 128 + 655360;
    // union A:
    //   phase 1 (prep..refine): xh (SECT ushorts) | knn32 (B*N*32 ushorts)
    //   phase 2 (gather..final): tmx | tmn
    ushort* xh    = (ushort*)uA;                         // SECT ushorts
    ushort* knn32 = (ushort*)(uA + SECT / 2);            // B*N*32 ushorts
    float*  tmx   = uA;                                  // SECT floats
    float*  tmn   = uA + SECT;                           // SECT floats

    hipMemsetAsync(S1, 0, 2 * 64 * sizeof(float), stream);
    k_ppz   <<<dim3(BATCH * (NPTS / 64)), dim3(256), 0, stream>>>(x, W, xt, xh, sq, pt, zt);
    k_knn   <<<dim3(BATCH * (NPTS / 16)), dim3(256), 0, stream>>>(xh, sq, knn32);
    k_refine<<<dim3((BATCH * NPTS) / 8), dim3(256), 0, stream>>>(xt, sq, knn32, idx20);
    k_gather<<<dim3(BATCH * (NPTS / 64)), dim3(256), 0, stream>>>(pt, zt, idx20, tmx, tmn, S1, S2);
    k_final <<<dim3(BATCH * (NPTS / 64)), dim3(256), 0, stream>>>(tmx, tmn, S1, S2, gamma, beta, out);
}